// Round 8
// baseline (821.054 us; speedup 1.0000x reference)
//
#include <hip/hip_runtime.h>
#include <hip/hip_cooperative_groups.h>
#include <stdint.h>

namespace cg = cooperative_groups;

// Problem constants
#define BB   256
#define NN   2048
#define MM   64
#define CC   512
#define OUTD 198
#define NUNITS (BB * 8)            // 8 work-units (256-row chunks) per batch

// Workspace layout (floats)
#define OS_STRIDE 200
#define OS_OFF    0                          // [B][200] raw controller outputs
#define P_OFF     (BB * OS_STRIDE)           // [B][N] p = exp(logit - beta)
#define SP_OFF    (P_OFF + BB * NN)          // [B][8] per-chunk sum(p)

typedef float vf4 __attribute__((ext_vector_type(4)));

__device__ __forceinline__ float softplusf(float x) {
    return x > 20.f ? x : log1pf(expf(x));
}
__device__ __forceinline__ float sigmoidf(float x) {
    return 1.f / (1.f + expf(-x));
}

// block sum over 4 waves of 64
__device__ __forceinline__ float bredsum(float v, float* red) {
    #pragma unroll
    for (int o = 32; o; o >>= 1) v += __shfl_down(v, o, 64);
    if ((threadIdx.x & 63) == 0) red[threadIdx.x >> 6] = v;
    __syncthreads();
    float r = red[0] + red[1] + red[2] + red[3];
    __syncthreads();
    return r;
}

// ---------------------------------------------------------------------------
// Phase A: controller matvec, distributed. unit (b,c): rows c*25..c*25+24.
// 8 lanes/row, shuffle reduce; raw outputs to ws (activations downstream).
// ---------------------------------------------------------------------------
__device__ __forceinline__ void phaseA(int u, const float* __restrict__ h,
        const float* __restrict__ Wm, const float* __restrict__ bias,
        float* __restrict__ ws, float* sm) {
    const int b = u >> 3, c = u & 7, t = threadIdx.x;
    __syncthreads();                       // protect sm from previous unit
    sm[t]       = h[(size_t)b * CC + t];
    sm[t + 256] = h[(size_t)b * CC + t + 256];
    __syncthreads();
    const int slot = t >> 3, l8 = t & 7, r = c * 25 + slot;
    if (slot < 25 && r < OUTD) {
        const float* wr = Wm + (size_t)r * CC + l8 * 64;
        const float* hp = sm + l8 * 64;
        float acc = 0.f;
        #pragma unroll
        for (int q = 0; q < 16; ++q) {
            const float4 p = *(const float4*)(wr + q * 4);
            acc += p.x * hp[q*4+0] + p.y * hp[q*4+1] + p.z * hp[q*4+2] + p.w * hp[q*4+3];
        }
        acc += __shfl_xor(acc, 1, 64);
        acc += __shfl_xor(acc, 2, 64);
        acc += __shfl_xor(acc, 4, 64);
        if (l8 == 0) ws[OS_OFF + b * OS_STRIDE + r] = acc + bias[r];
    }
}

// ---------------------------------------------------------------------------
// Phase B: content logits for unit's 256 rows. Softmax shift is FIXED at
// beta (logit = beta*cos <= beta, softmax is shift-invariant; beta is O(1)
// for this data so exp(lg-beta) in [e^-2b,1] - no under/overflow). This
// removes the global max reduction: chunk partials merge by pure addition.
// Stores p = exp(lg-beta) and chunk sum(p). Normal caching loads pull
// `memory` into LLC for phase C's re-read.
// ---------------------------------------------------------------------------
__device__ __forceinline__ void phaseB(int u, const float* __restrict__ mem,
        float* __restrict__ ws, float* sm) {
    const int b = u >> 3, c = u & 7, t = threadIdx.x;
    float* kk = sm;            // [64] k + 1e-16
    float* sc = sm + 64;       // 0:knorm 1:beta
    float* red = sm + 72;      // [4]
    const float* osb = ws + OS_OFF + (size_t)b * OS_STRIDE;
    __syncthreads();
    if (t < 64) {
        const float kv = osb[t] + 1e-16f;
        kk[t] = kv;
        float ssq = kv * kv;
        #pragma unroll
        for (int o = 32; o; o >>= 1) ssq += __shfl_xor(ssq, o, 64);
        if (t == 0) sc[0] = sqrtf(ssq);
    } else if (t == 64) {
        sc[1] = softplusf(osb[64]);
    }
    __syncthreads();
    const int l = t & 15, grp = t >> 4;
    const float kv0 = kk[4*l], kv1 = kk[4*l+1], kv2 = kk[4*l+2], kv3 = kk[4*l+3];
    const float knorm = sc[0], beta = sc[1];
    float psum = 0.f;
    #pragma unroll 4
    for (int it = 0; it < 16; ++it) {
        const int row = c * 256 + it * 16 + grp;
        const float4 p = *(const float4*)(mem + ((size_t)b * NN + row) * MM + 4 * l);
        const float m0 = p.x + 1e-16f, m1 = p.y + 1e-16f;
        const float m2 = p.z + 1e-16f, m3 = p.w + 1e-16f;
        float dot = m0 * kv0 + m1 * kv1 + m2 * kv2 + m3 * kv3;
        float ssq = m0 * m0 + m1 * m1 + m2 * m2 + m3 * m3;
        #pragma unroll
        for (int o = 1; o < 16; o <<= 1) {
            dot += __shfl_xor(dot, o, 64);
            ssq += __shfl_xor(ssq, o, 64);
        }
        if (l == 0) {
            const float lg = beta * dot / fmaxf(sqrtf(ssq) * knorm, 1e-8f);
            const float pv = expf(lg - beta);
            ws[P_OFF + (size_t)b * NN + row] = pv;
            psum += pv;
        }
    }
    const float tot = bredsum(psum, red);
    if (t == 0) ws[SP_OFF + b * 8 + c] = tot;
}

// ---------------------------------------------------------------------------
// Phase C: merge sum(p) partials; build FULL-batch w_g in LDS (redundant per
// block, all L2-hot); conv3+sharpen full batch -> local sharpen-sum (no third
// sync needed; fp-identical across the batch's 8 blocks); normalize; write w
// slice + erase/add stream for this unit's 256 rows (LLC-hot re-read, NT
// stores so mem_out doesn't evict `memory`).
// ---------------------------------------------------------------------------
__device__ __forceinline__ void phaseC(int u, const float* __restrict__ w_prev,
        const float* __restrict__ mem, float* __restrict__ ws,
        float* __restrict__ w_out, float* __restrict__ mem_out, float* sm) {
    const int b = u >> 3, c = u & 7, t = threadIdx.x;
    float* wg  = sm;           // [2050]  wg[j] = w_g[(j-1) mod N]
    float* sc  = sm + 2050;    // 0:g 1:gamma 2..4:s 5:inv1
    float* ee  = sm + 2064;    // [64] 16B-aligned
    float* aa  = sm + 2128;    // [64]
    float* red = sm + 2192;    // [4]
    const float* osb = ws + OS_OFF + (size_t)b * OS_STRIDE;
    __syncthreads();
    if (t == 0) {
        float S1 = 0.f;
        #pragma unroll
        for (int j = 0; j < 8; ++j) S1 += ws[SP_OFF + b * 8 + j];
        sc[5] = 1.f / S1;
        sc[0] = sigmoidf(osb[65]);
        sc[1] = 1.f + softplusf(osb[69]);
        const float x0 = osb[66], x1 = osb[67], x2 = osb[68];
        const float mx = fmaxf(x0, fmaxf(x1, x2));
        const float e0 = expf(x0 - mx), e1 = expf(x1 - mx), e2 = expf(x2 - mx);
        const float iv = 1.f / (e0 + e1 + e2);
        sc[2] = e0 * iv; sc[3] = e1 * iv; sc[4] = e2 * iv;
    } else if (t >= 64 && t < 128) {
        ee[t - 64] = sigmoidf(osb[70 + (t - 64)]);
    } else if (t >= 128 && t < 192) {
        aa[t - 128] = osb[134 + (t - 128)];
    }
    __syncthreads();
    const float g = sc[0], gamma = sc[1];
    const float s0 = sc[2], s1 = sc[3], s2 = sc[4], inv1 = sc[5];

    for (int j = t; j < 2050; j += 256) {
        const int r = (j + NN - 1) & (NN - 1);
        const float wc = ws[P_OFF + (size_t)b * NN + r] * inv1;
        wg[j] = g * wc + (1.f - g) * w_prev[(size_t)b * NN + r];
    }
    __syncthreads();

    float myw = 0.f, pp = 0.f;
    #pragma unroll
    for (int i = 0; i < 8; ++i) {
        const int n = t + i * 256;
        const float wt = wg[n] * s0 + wg[n + 1] * s1 + wg[n + 2] * s2;
        const float wsv = (wt > 0.f) ? exp2f(gamma * log2f(wt)) : 0.f;
        pp += wsv;
        if (i == c) myw = wsv;
    }
    const float ptot = bredsum(pp, red);
    const float invp = 1.f / (ptot + 1e-16f);
    const float wfin = myw * invp;
    w_out[(size_t)b * NN + c * 256 + t] = wfin;
    __syncthreads();               // all reads of wg done
    wg[t] = wfin;                  // reuse as w-slice broadcast buffer
    __syncthreads();

    const int seg = t & 15, rs = t >> 4;
    const vf4 ev = *(const vf4*)&ee[4 * seg];
    const vf4 av = *(const vf4*)&aa[4 * seg];
    const float* mb = mem + ((size_t)b * NN + c * 256) * MM + 4 * seg;
    float* ob = mem_out + ((size_t)b * NN + c * 256) * MM + 4 * seg;
    #pragma unroll 4
    for (int it = 0; it < 16; ++it) {
        const int rr = it * 16 + rs;
        const float w = wg[rr];
        const float4 p = *(const float4*)(mb + (size_t)rr * MM);
        vf4 o;
        o.x = p.x * (1.f - w * ev.x) + w * av.x;
        o.y = p.y * (1.f - w * ev.y) + w * av.y;
        o.z = p.z * (1.f - w * ev.z) + w * av.z;
        o.w = p.w * (1.f - w * ev.w) + w * av.w;
        __builtin_nontemporal_store(o, (vf4*)(ob + (size_t)rr * MM));
    }
}

// ---------------------------------------------------------------------------
// Cooperative kernel: all three phases at 8 blocks/CU (32 waves), separated
// by grid.sync() instead of kernel boundaries. Grid-stride loops tolerate
// any grid clamp from the occupancy query.
// ---------------------------------------------------------------------------
__global__ __launch_bounds__(256, 8) void k_coop(
        const float* __restrict__ h, const float* __restrict__ w_prev,
        const float* __restrict__ mem, const float* __restrict__ Wm,
        const float* __restrict__ bias, float* __restrict__ ws,
        float* __restrict__ w_out, float* __restrict__ mem_out) {
    cg::grid_group grid = cg::this_grid();
    __shared__ __align__(16) float sm[2208];
    for (int u = blockIdx.x; u < NUNITS; u += gridDim.x) phaseA(u, h, Wm, bias, ws, sm);
    __threadfence();
    grid.sync();
    __threadfence();
    for (int u = blockIdx.x; u < NUNITS; u += gridDim.x) phaseB(u, mem, ws, sm);
    __threadfence();
    grid.sync();
    __threadfence();
    for (int u = blockIdx.x; u < NUNITS; u += gridDim.x) phaseC(u, w_prev, mem, ws, w_out, mem_out, sm);
}

// Non-cooperative fallback wrappers (kernel boundaries as syncs)
__global__ __launch_bounds__(256, 8) void kA(
        const float* __restrict__ h, const float* __restrict__ Wm,
        const float* __restrict__ bias, float* __restrict__ ws) {
    __shared__ __align__(16) float sm[2208];
    for (int u = blockIdx.x; u < NUNITS; u += gridDim.x) phaseA(u, h, Wm, bias, ws, sm);
}
__global__ __launch_bounds__(256, 8) void kB(
        const float* __restrict__ mem, float* __restrict__ ws) {
    __shared__ __align__(16) float sm[2208];
    for (int u = blockIdx.x; u < NUNITS; u += gridDim.x) phaseB(u, mem, ws, sm);
}
__global__ __launch_bounds__(256, 8) void kC(
        const float* __restrict__ w_prev, const float* __restrict__ mem,
        float* __restrict__ ws, float* __restrict__ w_out,
        float* __restrict__ mem_out) {
    __shared__ __align__(16) float sm[2208];
    for (int u = blockIdx.x; u < NUNITS; u += gridDim.x) phaseC(u, w_prev, mem, ws, w_out, mem_out, sm);
}

extern "C" void kernel_launch(void* const* d_in, const int* in_sizes, int n_in,
                              void* d_out, int out_size, void* d_ws, size_t ws_size,
                              hipStream_t stream) {
    const float* h      = (const float*)d_in[0];
    const float* w_prev = (const float*)d_in[1];
    const float* memory = (const float*)d_in[2];
    const float* W      = (const float*)d_in[3];
    const float* bias   = (const float*)d_in[4];
    float* out = (float*)d_out;
    float* ws  = (float*)d_ws;

    float* w_out   = out;                       // [B,N]
    float* mem_out = out + (size_t)BB * NN;     // [B,N,M]

    static int gridB = -1;
    static int useCoop = 1;
    if (gridB < 0) {
        int dev = 0;
        (void)hipGetDevice(&dev);
        hipDeviceProp_t prop;
        (void)hipGetDeviceProperties(&prop, dev);
        int maxB = 0;
        if (hipOccupancyMaxActiveBlocksPerMultiprocessor(&maxB, (const void*)k_coop, 256, 0)
                != hipSuccess || maxB < 1) maxB = 1;
        long cap = (long)maxB * (long)prop.multiProcessorCount;
        gridB = (int)(cap < NUNITS ? cap : NUNITS);
        if (gridB < 1) gridB = 256;
        int coopAttr = 0;
        (void)hipDeviceGetAttribute(&coopAttr, hipDeviceAttributeCooperativeLaunch, dev);
        if (!coopAttr) useCoop = 0;
    }

    if (useCoop) {
        void* args[] = {(void*)&h, (void*)&w_prev, (void*)&memory, (void*)&W,
                        (void*)&bias, (void*)&ws, (void*)&w_out, (void*)&mem_out};
        if (hipLaunchCooperativeKernel((const void*)k_coop, dim3(gridB), dim3(256),
                                       args, 0, stream) != hipSuccess) {
            useCoop = 0;
            (void)hipGetLastError();
        }
    }
    if (!useCoop) {
        kA<<<NUNITS, 256, 0, stream>>>(h, W, bias, ws);
        kB<<<NUNITS, 256, 0, stream>>>(memory, ws);
        kC<<<NUNITS, 256, 0, stream>>>(w_prev, memory, ws, w_out, mem_out);
    }
}